// Round 1
// baseline (152.534 us; speedup 1.0000x reference)
//
#include <hip/hip_runtime.h>

#define N 8192
#define ROW_F4 (N / 4)          // 2048 float4 per row
#define LOG2_ROW_F4 11

// Kernel 1: one wave (64 lanes) per row. Each lane loads 32 float4 (128 floats),
// sums in f32, then 6-step shfl_xor wave reduction. Lane 0 writes d^-1/2.
__global__ __launch_bounds__(256) void rowsum_kernel(const float* __restrict__ A,
                                                     float* __restrict__ dinv) {
    const int wave = threadIdx.x >> 6;
    const int lane = threadIdx.x & 63;
    const int row  = blockIdx.x * 4 + wave;   // grid = N/4 blocks of 4 waves

    const float4* arow = reinterpret_cast<const float4*>(A + (size_t)row * N);

    float s = 0.0f;
#pragma unroll
    for (int k = 0; k < 32; ++k) {
        float4 v = arow[k * 64 + lane];       // lanes contiguous -> 1KiB/wave/instr
        s += (v.x + v.y) + (v.z + v.w);
    }

#pragma unroll
    for (int off = 32; off >= 1; off >>= 1)
        s += __shfl_xor(s, off, 64);

    if (lane == 0)
        dinv[row] = 1.0f / sqrtf(s);
}

// Kernel 2: out[i][j] = dinv[i] * A[i][j] * dinv[j], vectorized float4,
// grid-stride. dinv (32 KB) stays hot in L1/L2.
__global__ __launch_bounds__(256) void scale_kernel(const float* __restrict__ A,
                                                    const float* __restrict__ dinv,
                                                    float* __restrict__ out) {
    const float4* a4   = reinterpret_cast<const float4*>(A);
    const float4* d4   = reinterpret_cast<const float4*>(dinv);
    float4*       o4   = reinterpret_cast<float4*>(out);

    const size_t total  = (size_t)N * ROW_F4;            // 16M float4
    const size_t stride = (size_t)gridDim.x * blockDim.x;

    for (size_t g = (size_t)blockIdx.x * blockDim.x + threadIdx.x; g < total; g += stride) {
        const int row = (int)(g >> LOG2_ROW_F4);
        const int c4  = (int)(g & (ROW_F4 - 1));

        const float  ri = dinv[row];
        const float4 cj = d4[c4];
        const float4 a  = a4[g];

        float4 o;
        o.x = a.x * ri * cj.x;
        o.y = a.y * ri * cj.y;
        o.z = a.z * ri * cj.z;
        o.w = a.w * ri * cj.w;
        o4[g] = o;
    }
}

extern "C" void kernel_launch(void* const* d_in, const int* in_sizes, int n_in,
                              void* d_out, int out_size, void* d_ws, size_t ws_size,
                              hipStream_t stream) {
    const float* A    = (const float*)d_in[0];
    float*       out  = (float*)d_out;
    float*       dinv = (float*)d_ws;   // N floats = 32 KB scratch

    // Pass 1: row sums -> d^-1/2
    rowsum_kernel<<<N / 4, 256, 0, stream>>>(A, dinv);

    // Pass 2: scale. 2048 blocks x 256 threads, grid-stride (32 f4/thread).
    scale_kernel<<<2048, 256, 0, stream>>>(A, dinv, out);
}

// Round 2
// 119.566 us; speedup vs baseline: 1.2757x; 1.2757x over previous
//
#include <hip/hip_runtime.h>

#define N 8192

typedef float f32x4 __attribute__((ext_vector_type(4)));

// Kernel 1: one wave (64 lanes) per row. Each lane loads 32 float4 (128 floats),
// sums in f32, 6-step shfl_xor wave reduction. Lane 0 writes d^-1/2.
// Normal (caching) loads on purpose: we WANT A allocated in L3 here.
__global__ __launch_bounds__(256) void rowsum_kernel(const float* __restrict__ A,
                                                     float* __restrict__ dinv) {
    const int wave = threadIdx.x >> 6;
    const int lane = threadIdx.x & 63;
    const int row  = blockIdx.x * 4 + wave;   // grid = N/4 blocks of 4 waves

    const f32x4* arow = reinterpret_cast<const f32x4*>(A + (size_t)row * N);

    float s = 0.0f;
#pragma unroll
    for (int k = 0; k < 32; ++k) {
        f32x4 v = arow[k * 64 + lane];        // lanes contiguous -> 1KiB/wave/instr
        s += (v.x + v.y) + (v.z + v.w);
    }

#pragma unroll
    for (int off = 32; off >= 1; off >>= 1)
        s += __shfl_xor(s, off, 64);

    if (lane == 0)
        dinv[row] = 1.0f / sqrtf(s);
}

// Kernel 2: one block per row. out[i][j] = dinv[i] * A[i][j] * dinv[j].
// A reads are normal (hit L3-resident copy from pass 1); out stores are
// NON-TEMPORAL so the 256 MiB write stream does not evict A from the
// 256 MiB Infinity Cache — keeps A L3-resident within and ACROSS replays.
__global__ __launch_bounds__(256) void scale_kernel(const float* __restrict__ A,
                                                    const float* __restrict__ dinv,
                                                    float* __restrict__ out) {
    const int row = blockIdx.x;
    const float ri = dinv[row];                       // uniform scalar load

    const f32x4* a4 = reinterpret_cast<const f32x4*>(A   + (size_t)row * N);
    const f32x4* d4 = reinterpret_cast<const f32x4*>(dinv);
    f32x4*       o4 = reinterpret_cast<f32x4*>(out + (size_t)row * N);

#pragma unroll
    for (int k = 0; k < 8; ++k) {
        const int idx = k * 256 + threadIdx.x;        // 2048 f4 per row
        f32x4 a = a4[idx];
        f32x4 c = d4[idx];                            // 32 KB, L1/L2-hot
        f32x4 o = a * ri * c;
        __builtin_nontemporal_store(o, &o4[idx]);
    }
}

extern "C" void kernel_launch(void* const* d_in, const int* in_sizes, int n_in,
                              void* d_out, int out_size, void* d_ws, size_t ws_size,
                              hipStream_t stream) {
    const float* A    = (const float*)d_in[0];
    float*       out  = (float*)d_out;
    float*       dinv = (float*)d_ws;   // N floats = 32 KB scratch

    // Pass 1: row sums -> d^-1/2 (allocates A into L3)
    rowsum_kernel<<<N / 4, 256, 0, stream>>>(A, dinv);

    // Pass 2: scale, nt-stores for out
    scale_kernel<<<N, 256, 0, stream>>>(A, dinv, out);
}